// Round 3
// baseline (1442.220 us; speedup 1.0000x reference)
//
#include <hip/hip_runtime.h>
#include <math.h>

#define T_LEN 3000
#define EDGE 15
#define EXT_LEN 3030
#define NF 97
#define NB 64
#define NH 256
#define NI 100
#define YSTRIDE 3032   // padded ext row so (+16 floats) is 16B-aligned
#define NSEQ (NF*NB)

// ---------------- Kernel 1: filtfilt (one thread = one (f,b) sequence) ----
// Software-pipelined: clean loops, 20-wide register chunks, 1-chunk lookahead.
// Recurrence arithmetic is expression-identical to round-1 (bit-identical out).
__global__ __launch_bounds__(64) void k_filtfilt(
    const float* __restrict__ x, const float* __restrict__ b_all,
    const float* __restrict__ a_all, const float* __restrict__ zi_all,
    float* __restrict__ Y)
{
    const int f = blockIdx.x;
    const int b = threadIdx.x;
    const double bc0 = b_all[f*5+0], bc1 = b_all[f*5+1], bc2 = b_all[f*5+2],
                 bc3 = b_all[f*5+3], bc4 = b_all[f*5+4];
    const double ac1 = a_all[f*5+1], ac2 = a_all[f*5+2],
                 ac3 = a_all[f*5+3], ac4 = a_all[f*5+4];
    const double zi0 = zi_all[f*4+0], zi1 = zi_all[f*4+1],
                 zi2 = zi_all[f*4+2], zi3 = zi_all[f*4+3];
    const float* xr = x + (size_t)b * T_LEN;
    float* y = Y + (size_t)(f * NB + b) * YSTRIDE + 1;   // ext index i lives at y[i]

    double z0, z1, z2, z3;

#define FSTEP(XV, DST) { double xv = (XV); \
    double yv = fma(bc0, xv, z0); \
    z0 = fma(bc1, xv, z1) - ac1*yv; \
    z1 = fma(bc2, xv, z2) - ac2*yv; \
    z2 = fma(bc3, xv, z3) - ac3*yv; \
    z3 = bc4*xv - ac4*yv; \
    DST = (float)yv; }

    const double x0 = (double)xr[0];
    const double xl = (double)xr[T_LEN-1];
    { const double e0 = 2.0*x0 - (double)xr[EDGE];
      z0 = zi0*e0; z1 = zi1*e0; z2 = zi2*e0; z3 = zi3*e0; }

    // left edge (15 steps)
    for (int i = 0; i < EDGE; ++i) {
        float o; FSTEP(2.0*x0 - (double)xr[EDGE - i], o); y[i] = o;
    }
    // main body: 3000 = 150 chunks of 20, prefetch next chunk during compute
    {
        float cur[20], nxt[20];
        #pragma unroll
        for (int j = 0; j < 20; ++j) cur[j] = xr[j];
        for (int k = 0; k < T_LEN; k += 20) {
            if (k + 20 < T_LEN) {
                #pragma unroll
                for (int j = 0; j < 20; ++j) nxt[j] = xr[k + 20 + j];
            }
            #pragma unroll
            for (int j = 0; j < 20; ++j) {
                float o; FSTEP((double)cur[j], o); y[EDGE + k + j] = o;
            }
            #pragma unroll
            for (int j = 0; j < 20; ++j) cur[j] = nxt[j];
        }
    }
    // right edge (15 steps)
    for (int i = 0; i < EDGE; ++i) {
        float o; FSTEP(2.0*xl - (double)xr[T_LEN - 2 - i], o); y[EDGE + T_LEN + i] = o;
    }

    // backward pass in place (reversed input, reversed output => same slot)
    const double yl = (double)y[EXT_LEN-1];
    z0 = zi0*yl; z1 = zi1*yl; z2 = zi2*yl; z3 = zi3*yl;
    {
        float bcur[20], bnxt[20];
        #pragma unroll
        for (int j = 0; j < 20; ++j) bcur[j] = y[3000 + j];   // chunk [3000..3019]
        // top 10 scalar: i = 3029..3020
        for (int i = EXT_LEN-1; i >= 3020; --i) {
            float o; FSTEP((double)y[i], o); y[i] = o;
        }
        // 151 chunks of 20 descending: k = 3019, 2999, ..., 19
        for (int k = 3019; k >= 19; k -= 20) {
            if (k >= 39) {
                #pragma unroll
                for (int j = 0; j < 20; ++j) bnxt[j] = y[k - 39 + j];
            }
            #pragma unroll
            for (int j = 19; j >= 0; --j) {
                float o; FSTEP((double)bcur[j], o); bcur[j] = o;
            }
            #pragma unroll
            for (int j = 0; j < 20; ++j) y[k - 19 + j] = bcur[j];
            #pragma unroll
            for (int j = 0; j < 20; ++j) bcur[j] = bnxt[j];
        }
    }
#undef FSTEP
}

// ---------------- Kernel 2: U[r][h] = (1-tanh^2(P[r]·W1[:,h]+b1))*w2 ------
// 1024 threads = 4 row-groups (g=tid>>8) x 4 rows; h = tid&255.
// Same sequential-K accumulation order per row => bit-identical to round 2.
// Explicit 1-ahead prefetch of uniform P chunks (SGPRs) and W1 lane loads.
__global__ __launch_bounds__(1024) void k_ugemm(
    const float* __restrict__ x, const float* __restrict__ Y,
    const float* __restrict__ W1, const float* __restrict__ b1,
    const float* __restrict__ w2, float* __restrict__ U)
{
    const int tid = threadIdx.x;
    const int h   = tid & 255;
    const int g   = tid >> 8;                  // row-group 0..3 (wave-uniform)
    const int r0  = blockIdx.x * 16 + g * 4;
    const float* p0;
    int pstride;
    if (r0 < NB) { p0 = x + (size_t)r0 * T_LEN;                pstride = T_LEN; }
    else         { p0 = Y + (size_t)(r0 - NB) * YSTRIDE + 16;  pstride = YSTRIDE; }
    float acc[4] = {};
    const float* wp = W1 + h;

    float4 pc[4][2], pn[4][2];
    float  wc[8], wn[8];
    #pragma unroll
    for (int rr = 0; rr < 4; ++rr) {
        pc[rr][0] = *(const float4*)(p0 + (size_t)rr*pstride);
        pc[rr][1] = *(const float4*)(p0 + (size_t)rr*pstride + 4);
    }
    #pragma unroll
    for (int j = 0; j < 8; ++j) wc[j] = wp[j*NH];

    for (int k = 0; k < T_LEN; k += 8) {
        const int kn = (k + 8 < T_LEN) ? k + 8 : 0;   // clamped prefetch addr
        #pragma unroll
        for (int rr = 0; rr < 4; ++rr) {
            pn[rr][0] = *(const float4*)(p0 + (size_t)rr*pstride + kn);
            pn[rr][1] = *(const float4*)(p0 + (size_t)rr*pstride + kn + 4);
        }
        #pragma unroll
        for (int j = 0; j < 8; ++j) wn[j] = wp[(kn + j)*NH];
        #pragma unroll
        for (int rr = 0; rr < 4; ++rr) {
            acc[rr] = fmaf(pc[rr][0].x, wc[0], acc[rr]);
            acc[rr] = fmaf(pc[rr][0].y, wc[1], acc[rr]);
            acc[rr] = fmaf(pc[rr][0].z, wc[2], acc[rr]);
            acc[rr] = fmaf(pc[rr][0].w, wc[3], acc[rr]);
            acc[rr] = fmaf(pc[rr][1].x, wc[4], acc[rr]);
            acc[rr] = fmaf(pc[rr][1].y, wc[5], acc[rr]);
            acc[rr] = fmaf(pc[rr][1].z, wc[6], acc[rr]);
            acc[rr] = fmaf(pc[rr][1].w, wc[7], acc[rr]);
        }
        #pragma unroll
        for (int rr = 0; rr < 4; ++rr) { pc[rr][0] = pn[rr][0]; pc[rr][1] = pn[rr][1]; }
        #pragma unroll
        for (int j = 0; j < 8; ++j) wc[j] = wn[j];
    }
    const float b1v = b1[h], w2e = w2[h];
    #pragma unroll
    for (int rr = 0; rr < 4; ++rr) {
        float th = tanhf(acc[rr] + b1v);
        U[(size_t)(r0+rr)*NH + h] = (1.f - th*th) * w2e;
    }
}

// ---------------- Kernel V: V[b][i][h] = 0.5*(u_row(i)+u_row(i+1)) --------
__global__ __launch_bounds__(256) void k_vbuild(
    const float* __restrict__ U, const float* __restrict__ b1,
    const float* __restrict__ w2, float* __restrict__ V)
{
    const int i = blockIdx.x;   // 0..99
    const int b = blockIdx.y;   // 0..63
    const int h = threadIdx.x;
    auto urow = [&](int ii) -> float {
        if (ii <= 2)  return U[(size_t)b*NH + h];
        if (ii <= 99) return U[(size_t)(NB + (ii-3)*NB + b)*NH + h];
        float th = tanhf(b1[h]);               // pseudo-row 100: p == 0
        return (1.f - th*th) * w2[h];
    };
    V[((size_t)b*NI + i)*NH + h] = 0.5f*(urow(i) + urow(i+1));
}

__device__ __forceinline__ float rowval(int i, int b, int t,
        const float* __restrict__ x, const float* __restrict__ Y)
{
    if (i <= 2)  return x[(size_t)b*T_LEN + t];
    if (i <= 99) return Y[(size_t)((i-3)*NB + b)*YSTRIDE + 16 + t];
    return 0.f;
}

// ---------------- Kernel 3: out[b][t][inv[i]] = (W1[t]·V[b][i]) * delta ---
// lanes = t (64 t per block), wave w handles i in [25w, 25w+25).
// W1 tile staged through LDS (shared by the 4 waves, coalesced loads).
__global__ __launch_bounds__(256) void k_out(
    const float* __restrict__ x, const float* __restrict__ Y,
    const float* __restrict__ W1, const float* __restrict__ V,
    const int* __restrict__ freq_index, float* __restrict__ out)
{
    __shared__ float sm[64*101 + 104];   // Ws (64x68=4352) / Os (64x101) union + inv
    float* Ws = sm;
    float* Os = sm;
    int*  inv = (int*)(sm + 64*101);
    const int tid = threadIdx.x;
    const int tb  = blockIdx.x;   // 0..46
    const int b   = blockIdx.y;   // 0..63
    if (tid < NI) inv[freq_index[tid]] = tid;
    __syncthreads();
    const int lane = tid & 63;
    const int w    = tid >> 6;    // 0..3
    const int wu   = __builtin_amdgcn_readfirstlane(w);   // force SGPR -> s_load V
    const int t    = tb*64 + lane;
    const bool tv  = t < T_LEN;
    const int t0   = tb*64;
    const float* vbase = V + ((size_t)b*NI + wu*25) * NH;
    float acc[25] = {};
    for (int kc = 0; kc < 4; ++kc) {
        __syncthreads();          // previous tile fully consumed
        #pragma unroll
        for (int m = 0; m < 4; ++m) {
            int q   = tid + 256*m;     // float4 id, 0..1023
            int row = q >> 4;
            int c4  = q & 15;
            int tg  = t0 + row;
            float4 wv = (tg < T_LEN)
                ? *(const float4*)(W1 + (size_t)tg*NH + kc*64 + c4*4)
                : make_float4(0.f,0.f,0.f,0.f);
            *(float4*)(Ws + row*68 + c4*4) = wv;
        }
        __syncthreads();
        #pragma unroll
        for (int k4 = 0; k4 < 16; ++k4) {
            float4 wv = *(const float4*)(Ws + lane*68 + k4*4);
            #pragma unroll
            for (int jj = 0; jj < 25; ++jj) {
                float4 vv = *(const float4*)(vbase + (size_t)jj*NH + kc*64 + k4*4);
                acc[jj] = fmaf(wv.x, vv.x, acc[jj]);
                acc[jj] = fmaf(wv.y, vv.y, acc[jj]);
                acc[jj] = fmaf(wv.z, vv.z, acc[jj]);
                acc[jj] = fmaf(wv.w, vv.w, acc[jj]);
            }
        }
    }
    __syncthreads();              // Ws reads done before Os overwrite
    if (tv) {
        const int i0 = wu*25;
        float rv = rowval(i0, b, t, x, Y);
        #pragma unroll
        for (int jj = 0; jj < 25; ++jj) {
            int i = i0 + jj;
            float rvn = rowval(i+1, b, t, x, Y);
            Os[lane*101 + inv[i]] = acc[jj] * (rv - rvn);
            rv = rvn;
        }
    }
    __syncthreads();
    const size_t obase = ((size_t)b*T_LEN + (size_t)tb*64) * NI;
    #pragma unroll
    for (int m = 0; m < 25; ++m) {
        int n  = tid + 256*m;      // 0..6399
        int t2 = n / 100;
        int j  = n - t2*100;
        if (tb*64 + t2 < T_LEN)
            out[obase + (size_t)t2*NI + j] = Os[t2*101 + j];
    }
}

extern "C" void kernel_launch(void* const* d_in, const int* in_sizes, int n_in,
                              void* d_out, int out_size, void* d_ws, size_t ws_size,
                              hipStream_t stream) {
    const float* x      = (const float*)d_in[0];
    const float* b_all  = (const float*)d_in[1];
    const float* a_all  = (const float*)d_in[2];
    const float* zi_all = (const float*)d_in[3];
    const float* W1     = (const float*)d_in[4];
    const float* b1     = (const float*)d_in[5];
    const float* w2     = (const float*)d_in[6];
    const int*   fidx   = (const int*)d_in[7];
    float* out = (float*)d_out;

    float* Y = (float*)d_ws;                         // NSEQ * YSTRIDE floats
    float* U = Y + (size_t)NSEQ * YSTRIDE;           // 6272 * 256 floats
    float* V = U + (size_t)(NB + NSEQ) * NH;         // 64*100*256 floats
    // total workspace: ~88.3 MB

    hipLaunchKernelGGL(k_filtfilt, dim3(NF), dim3(NB), 0, stream,
                       x, b_all, a_all, zi_all, Y);
    hipLaunchKernelGGL(k_ugemm, dim3((NB + NSEQ)/16), dim3(1024), 0, stream,
                       x, Y, W1, b1, w2, U);
    hipLaunchKernelGGL(k_vbuild, dim3(NI, NB), dim3(NH), 0, stream,
                       U, b1, w2, V);
    hipLaunchKernelGGL(k_out, dim3((T_LEN+63)/64, NB), dim3(256), 0, stream,
                       x, Y, W1, V, fidx, out);
}

// Round 4
// 873.738 us; speedup vs baseline: 1.6506x; 1.6506x over previous
//
#include <hip/hip_runtime.h>
#include <math.h>

#define T_LEN 3000
#define EDGE 15
#define EXT_LEN 3030
#define NF 97
#define NB 64
#define NH 256
#define NI 100
#define YSTRIDE 3032   // padded ext row so (+16 floats) is 16B-aligned
#define NSEQ (NF*NB)
#define BK 120         // 3000 = 25 * 120 exactly; 120 floats = 30 float4

// ---------------- Kernel 1: filtfilt (one thread = one (f,b) sequence) ----
// Software-pipelined: clean loops, 20-wide register chunks, 1-chunk lookahead.
__global__ __launch_bounds__(64) void k_filtfilt(
    const float* __restrict__ x, const float* __restrict__ b_all,
    const float* __restrict__ a_all, const float* __restrict__ zi_all,
    float* __restrict__ Y)
{
    const int f = blockIdx.x;
    const int b = threadIdx.x;
    const double bc0 = b_all[f*5+0], bc1 = b_all[f*5+1], bc2 = b_all[f*5+2],
                 bc3 = b_all[f*5+3], bc4 = b_all[f*5+4];
    const double ac1 = a_all[f*5+1], ac2 = a_all[f*5+2],
                 ac3 = a_all[f*5+3], ac4 = a_all[f*5+4];
    const double zi0 = zi_all[f*4+0], zi1 = zi_all[f*4+1],
                 zi2 = zi_all[f*4+2], zi3 = zi_all[f*4+3];
    const float* xr = x + (size_t)b * T_LEN;
    float* y = Y + (size_t)(f * NB + b) * YSTRIDE + 1;   // ext index i lives at y[i]

    double z0, z1, z2, z3;

#define FSTEP(XV, DST) { double xv = (XV); \
    double yv = fma(bc0, xv, z0); \
    z0 = fma(bc1, xv, z1) - ac1*yv; \
    z1 = fma(bc2, xv, z2) - ac2*yv; \
    z2 = fma(bc3, xv, z3) - ac3*yv; \
    z3 = bc4*xv - ac4*yv; \
    DST = (float)yv; }

    const double x0 = (double)xr[0];
    const double xl = (double)xr[T_LEN-1];
    { const double e0 = 2.0*x0 - (double)xr[EDGE];
      z0 = zi0*e0; z1 = zi1*e0; z2 = zi2*e0; z3 = zi3*e0; }

    // left edge (15 steps)
    for (int i = 0; i < EDGE; ++i) {
        float o; FSTEP(2.0*x0 - (double)xr[EDGE - i], o); y[i] = o;
    }
    // main body: 3000 = 150 chunks of 20, prefetch next chunk during compute
    {
        float cur[20], nxt[20];
        #pragma unroll
        for (int j = 0; j < 20; ++j) cur[j] = xr[j];
        for (int k = 0; k < T_LEN; k += 20) {
            if (k + 20 < T_LEN) {
                #pragma unroll
                for (int j = 0; j < 20; ++j) nxt[j] = xr[k + 20 + j];
            }
            #pragma unroll
            for (int j = 0; j < 20; ++j) {
                float o; FSTEP((double)cur[j], o); y[EDGE + k + j] = o;
            }
            #pragma unroll
            for (int j = 0; j < 20; ++j) cur[j] = nxt[j];
        }
    }
    // right edge (15 steps)
    for (int i = 0; i < EDGE; ++i) {
        float o; FSTEP(2.0*xl - (double)xr[T_LEN - 2 - i], o); y[EDGE + T_LEN + i] = o;
    }

    // backward pass in place (reversed input, reversed output => same slot)
    const double yl = (double)y[EXT_LEN-1];
    z0 = zi0*yl; z1 = zi1*yl; z2 = zi2*yl; z3 = zi3*yl;
    {
        float bcur[20], bnxt[20];
        #pragma unroll
        for (int j = 0; j < 20; ++j) bcur[j] = y[3000 + j];   // chunk [3000..3019]
        for (int i = EXT_LEN-1; i >= 3020; --i) {
            float o; FSTEP((double)y[i], o); y[i] = o;
        }
        for (int k = 3019; k >= 19; k -= 20) {
            if (k >= 39) {
                #pragma unroll
                for (int j = 0; j < 20; ++j) bnxt[j] = y[k - 39 + j];
            }
            #pragma unroll
            for (int j = 19; j >= 0; --j) {
                float o; FSTEP((double)bcur[j], o); bcur[j] = o;
            }
            #pragma unroll
            for (int j = 0; j < 20; ++j) y[k - 19 + j] = bcur[j];
            #pragma unroll
            for (int j = 0; j < 20; ++j) bcur[j] = bnxt[j];
        }
    }
#undef FSTEP
}

// ---------------- Kernel 2: U[r][h] = (1-tanh^2(P[r]·W1[:,h]+b1))*w2 ------
// 512 threads = 8 waves. h = tid&255 (lane-coalesced W1), g = tid>>8 picks
// 8 rows. P tile (16 rows x BK) double-buffered in LDS; P reads are wave
// broadcasts (all lanes same addr). K strictly ascending per (row,h) =>
// bit-identical to previous rounds.
__global__ __launch_bounds__(512) void k_ugemm(
    const float* __restrict__ x, const float* __restrict__ Y,
    const float* __restrict__ W1, const float* __restrict__ b1,
    const float* __restrict__ w2, float* __restrict__ U)
{
    __shared__ float Pl[2][16*BK];
    const int tid = threadIdx.x;
    const int h   = tid & 255;
    const int g   = tid >> 8;                  // 0..1 -> rows g*8..g*8+7
    const int r0  = blockIdx.x * 16;
    const float* p0;
    int pstride;
    if (r0 < NB) { p0 = x + (size_t)r0 * T_LEN;                pstride = T_LEN; }
    else         { p0 = Y + (size_t)(r0 - NB) * YSTRIDE + 16;  pstride = YSTRIDE; }

    // staging role: row rt = tid>>5 (0..15), float4-col ct = tid&31 (<30 active)
    const int rt = tid >> 5;
    const int ct = tid & 31;
    const bool stg = (ct < 30);
    const float* gsrc = p0 + (size_t)rt * pstride + ct*4;

    float acc[8] = {};
    const float* wbase = W1 + h;

    float4 v;
    if (stg) v = *(const float4*)(gsrc);       // chunk 0
    if (stg) *(float4*)&Pl[0][rt*BK + ct*4] = v;

    int cur = 0;
    for (int c = 0; c < 25; ++c) {
        float4 nxt;
        if (c < 24 && stg) nxt = *(const float4*)(gsrc + (c+1)*BK);
        __syncthreads();                       // Pl[cur] ready; prev reads done
        const int k0 = c * BK;
        #pragma unroll 5
        for (int k4 = 0; k4 < 30; ++k4) {
            float4 p[8];
            #pragma unroll
            for (int j = 0; j < 8; ++j)
                p[j] = *(const float4*)&Pl[cur][(g*8+j)*BK + k4*4];
            const float* wk = wbase + (size_t)(k0 + k4*4) * NH;
            float w0 = wk[0], w1v = wk[NH], w2v = wk[2*NH], w3 = wk[3*NH];
            #pragma unroll
            for (int j = 0; j < 8; ++j) acc[j] = fmaf(p[j].x, w0,  acc[j]);
            #pragma unroll
            for (int j = 0; j < 8; ++j) acc[j] = fmaf(p[j].y, w1v, acc[j]);
            #pragma unroll
            for (int j = 0; j < 8; ++j) acc[j] = fmaf(p[j].z, w2v, acc[j]);
            #pragma unroll
            for (int j = 0; j < 8; ++j) acc[j] = fmaf(p[j].w, w3,  acc[j]);
        }
        if (c < 24) {
            if (stg) *(float4*)&Pl[cur^1][rt*BK + ct*4] = nxt;
            cur ^= 1;
        }
    }
    const float b1v = b1[h], w2e = w2[h];
    #pragma unroll
    for (int j = 0; j < 8; ++j) {
        float th = tanhf(acc[j] + b1v);
        U[(size_t)(r0 + g*8 + j)*NH + h] = (1.f - th*th) * w2e;
    }
}

// ---------------- Kernel V: V[b][i][h] = 0.5*(u_row(i)+u_row(i+1)) --------
__global__ __launch_bounds__(256) void k_vbuild(
    const float* __restrict__ U, const float* __restrict__ b1,
    const float* __restrict__ w2, float* __restrict__ V)
{
    const int i = blockIdx.x;   // 0..99
    const int b = blockIdx.y;   // 0..63
    const int h = threadIdx.x;
    auto urow = [&](int ii) -> float {
        if (ii <= 2)  return U[(size_t)b*NH + h];
        if (ii <= 99) return U[(size_t)(NB + (ii-3)*NB + b)*NH + h];
        float th = tanhf(b1[h]);               // pseudo-row 100: p == 0
        return (1.f - th*th) * w2[h];
    };
    V[((size_t)b*NI + i)*NH + h] = 0.5f*(urow(i) + urow(i+1));
}

__device__ __forceinline__ float rowval(int i, int b, int t,
        const float* __restrict__ x, const float* __restrict__ Y)
{
    if (i <= 2)  return x[(size_t)b*T_LEN + t];
    if (i <= 99) return Y[(size_t)((i-3)*NB + b)*YSTRIDE + 16 + t];
    return 0.f;
}

// ---------------- Kernel 3: out[b][t][inv[i]] = (W1[t]·V[b][i]) * delta ---
__global__ __launch_bounds__(256) void k_out(
    const float* __restrict__ x, const float* __restrict__ Y,
    const float* __restrict__ W1, const float* __restrict__ V,
    const int* __restrict__ freq_index, float* __restrict__ out)
{
    __shared__ float sm[64*101 + 104];   // Ws (64x68=4352) / Os (64x101) union + inv
    float* Ws = sm;
    float* Os = sm;
    int*  inv = (int*)(sm + 64*101);
    const int tid = threadIdx.x;
    const int tb  = blockIdx.x;   // 0..46
    const int b   = blockIdx.y;   // 0..63
    if (tid < NI) inv[freq_index[tid]] = tid;
    __syncthreads();
    const int lane = tid & 63;
    const int w    = tid >> 6;    // 0..3
    const int wu   = __builtin_amdgcn_readfirstlane(w);   // force SGPR -> s_load V
    const int t    = tb*64 + lane;
    const bool tv  = t < T_LEN;
    const int t0   = tb*64;
    const float* vbase = V + ((size_t)b*NI + wu*25) * NH;
    float acc[25] = {};
    for (int kc = 0; kc < 4; ++kc) {
        __syncthreads();          // previous tile fully consumed
        #pragma unroll
        for (int m = 0; m < 4; ++m) {
            int q   = tid + 256*m;     // float4 id, 0..1023
            int row = q >> 4;
            int c4  = q & 15;
            int tg  = t0 + row;
            float4 wv = (tg < T_LEN)
                ? *(const float4*)(W1 + (size_t)tg*NH + kc*64 + c4*4)
                : make_float4(0.f,0.f,0.f,0.f);
            *(float4*)(Ws + row*68 + c4*4) = wv;
        }
        __syncthreads();
        #pragma unroll
        for (int k4 = 0; k4 < 16; ++k4) {
            float4 wv = *(const float4*)(Ws + lane*68 + k4*4);
            #pragma unroll
            for (int jj = 0; jj < 25; ++jj) {
                float4 vv = *(const float4*)(vbase + (size_t)jj*NH + kc*64 + k4*4);
                acc[jj] = fmaf(wv.x, vv.x, acc[jj]);
                acc[jj] = fmaf(wv.y, vv.y, acc[jj]);
                acc[jj] = fmaf(wv.z, vv.z, acc[jj]);
                acc[jj] = fmaf(wv.w, vv.w, acc[jj]);
            }
        }
    }
    __syncthreads();              // Ws reads done before Os overwrite
    if (tv) {
        const int i0 = wu*25;
        float rv = rowval(i0, b, t, x, Y);
        #pragma unroll
        for (int jj = 0; jj < 25; ++jj) {
            int i = i0 + jj;
            float rvn = rowval(i+1, b, t, x, Y);
            Os[lane*101 + inv[i]] = acc[jj] * (rv - rvn);
            rv = rvn;
        }
    }
    __syncthreads();
    const size_t obase = ((size_t)b*T_LEN + (size_t)tb*64) * NI;
    #pragma unroll
    for (int m = 0; m < 25; ++m) {
        int n  = tid + 256*m;      // 0..6399
        int t2 = n / 100;
        int j  = n - t2*100;
        if (tb*64 + t2 < T_LEN)
            out[obase + (size_t)t2*NI + j] = Os[t2*101 + j];
    }
}

extern "C" void kernel_launch(void* const* d_in, const int* in_sizes, int n_in,
                              void* d_out, int out_size, void* d_ws, size_t ws_size,
                              hipStream_t stream) {
    const float* x      = (const float*)d_in[0];
    const float* b_all  = (const float*)d_in[1];
    const float* a_all  = (const float*)d_in[2];
    const float* zi_all = (const float*)d_in[3];
    const float* W1     = (const float*)d_in[4];
    const float* b1     = (const float*)d_in[5];
    const float* w2     = (const float*)d_in[6];
    const int*   fidx   = (const int*)d_in[7];
    float* out = (float*)d_out;

    float* Y = (float*)d_ws;                         // NSEQ * YSTRIDE floats
    float* U = Y + (size_t)NSEQ * YSTRIDE;           // 6272 * 256 floats
    float* V = U + (size_t)(NB + NSEQ) * NH;         // 64*100*256 floats
    // total workspace: ~88.3 MB

    hipLaunchKernelGGL(k_filtfilt, dim3(NF), dim3(NB), 0, stream,
                       x, b_all, a_all, zi_all, Y);
    hipLaunchKernelGGL(k_ugemm, dim3((NB + NSEQ)/16), dim3(512), 0, stream,
                       x, Y, W1, b1, w2, U);
    hipLaunchKernelGGL(k_vbuild, dim3(NI, NB), dim3(NH), 0, stream,
                       U, b1, w2, V);
    hipLaunchKernelGGL(k_out, dim3((T_LEN+63)/64, NB), dim3(256), 0, stream,
                       x, Y, W1, V, fidx, out);
}